// Round 9
// baseline (509.668 us; speedup 1.0000x reference)
//
#include <hip/hip_runtime.h>
#include <hip/hip_bf16.h>
#include <math.h>

// Problem: B=2, S=2048, D=1024, H=16, hd=64
#define BB 2
#define SS 2048
#define DD 1024
#define HH 16
#define HD 64
#define MM (BB*SS)      // 4096
#define N3 (3*DD)       // 3072

using bf16x8 = __attribute__((ext_vector_type(8))) short;
using f32x4  = __attribute__((ext_vector_type(4))) float;
using f32x16 = __attribute__((ext_vector_type(16))) float;

union U128 { uint4 u; bf16x8 v; };

#define GLOBAL_AS __attribute__((address_space(1)))
#define LDS_AS    __attribute__((address_space(3)))

__device__ __forceinline__ void gload_lds16(const void* g, void* l) {
    __builtin_amdgcn_global_load_lds((const GLOBAL_AS void*)g, (LDS_AS void*)l, 16, 0, 0);
}

__device__ __forceinline__ unsigned short f2bf(float f) {
    union { float f; unsigned int u; } x; x.f = f;
    unsigned int u = x.u;
    unsigned int r = (u + 0x7fffu + ((u >> 16) & 1u)) >> 16;   // RNE
    return (unsigned short)r;
}
__device__ __forceinline__ float fromraw(unsigned int u) {
    union { unsigned int u; float f; } x; x.u = u; return x.f;
}
__device__ __forceinline__ f32x16 zero16() {
    f32x16 v;
#pragma unroll
    for (int i = 0; i < 16; ++i) v[i] = 0.f;
    return v;
}

// ---------------------------------------------------------------------------
// Elementwise fp32 -> bf16 cast (8 elems/thread). n must be divisible by 2048.
// ---------------------------------------------------------------------------
__global__ __launch_bounds__(256)
void cast_bf16_kernel(const float* __restrict__ X, unsigned short* __restrict__ Y)
{
    int i = blockIdx.x * 256 + threadIdx.x;
    const float4 a = ((const float4*)X)[i * 2];
    const float4 b = ((const float4*)X)[i * 2 + 1];
    uint4 o;
    o.x = (unsigned)f2bf(a.x) | ((unsigned)f2bf(a.y) << 16);
    o.y = (unsigned)f2bf(a.z) | ((unsigned)f2bf(a.w) << 16);
    o.z = (unsigned)f2bf(b.x) | ((unsigned)f2bf(b.y) << 16);
    o.w = (unsigned)f2bf(b.z) | ((unsigned)f2bf(b.w) << 16);
    ((uint4*)Y)[i] = o;
}

// ---------------------------------------------------------------------------
// Transpose+cast: W[K][N] fp32 -> Wt[N][K] bf16.  32x32 tiles, 256 threads.
// ---------------------------------------------------------------------------
__global__ __launch_bounds__(256)
void transpose_cast_kernel(const float* __restrict__ W, unsigned short* __restrict__ Wt,
                           int K, int N)
{
    __shared__ float t[32][33];
    const int n0 = blockIdx.x * 32, k0 = blockIdx.y * 32;
    const int tr = threadIdx.x >> 3, c4 = (threadIdx.x & 7) * 4;
    float4 v = *(const float4*)(W + (size_t)(k0 + tr) * N + n0 + c4);
    t[tr][c4 + 0] = v.x; t[tr][c4 + 1] = v.y; t[tr][c4 + 2] = v.z; t[tr][c4 + 3] = v.w;
    __syncthreads();
    unsigned int o0 = (unsigned)f2bf(t[c4 + 0][tr]) | ((unsigned)f2bf(t[c4 + 1][tr]) << 16);
    unsigned int o1 = (unsigned)f2bf(t[c4 + 2][tr]) | ((unsigned)f2bf(t[c4 + 3][tr]) << 16);
    uint2 o; o.x = o0; o.y = o1;
    *(uint2*)(Wt + (size_t)(n0 + tr) * K + k0 + c4) = o;
}

// ---------------------------------------------------------------------------
// bf16 MFMA GEMM:  C[M][N] = A[M][K] @ Bt[N][K]^T + bias[N]
// A, Bt bf16 row-major (both k-contiguous).  128x128 tile, BK=64, 4 waves 2x2.
// LDS tiles [128 rows][64 k] with 16B-chunk XOR swizzle (chunk ^= row&7),
// staged via global_load_lds with pre-swizzled global source addresses.
// OUT_BF16: 1 -> bf16 output, 0 -> fp32 output.
// ---------------------------------------------------------------------------
template<int OUT_BF16>
__global__ __launch_bounds__(256)
void gemm_bf16(const unsigned short* __restrict__ A, const unsigned short* __restrict__ Bt,
               const float* __restrict__ bias, void* __restrict__ Cout,
               int M, int N, int K)
{
    __shared__ unsigned short As[128 * 64];
    __shared__ unsigned short Bs[128 * 64];

    const int tid = threadIdx.x;
    const int w = tid >> 6, ln = tid & 63;
    const int m0 = blockIdx.y * 128, n0 = blockIdx.x * 128;
    const int wr = w >> 1, wc = w & 1;
    const int l15 = ln & 15, l4 = ln >> 4, l7 = ln & 7;

    f32x4 acc[4][4];
#pragma unroll
    for (int m = 0; m < 4; ++m)
#pragma unroll
        for (int n = 0; n < 4; ++n) {
            f32x4 z = {0.f, 0.f, 0.f, 0.f};
            acc[m][n] = z;
        }

    for (int k0 = 0; k0 < K; k0 += 64) {
        // stage A and B tiles (each 16KB = 1024 16B-slots; 4 instrs/wave each)
#pragma unroll
        for (int r = 0; r < 4; ++r) {
            const int slot = w * 256 + r * 64 + ln;
            const int row = slot >> 3, ch = slot & 7;
            const int cs = ch ^ (row & 7);                 // pre-swizzled source chunk
            gload_lds16(A + (size_t)(m0 + row) * K + k0 + cs * 8,
                        (char*)As + (w * 256 + r * 64) * 16);
            gload_lds16(Bt + (size_t)(n0 + row) * K + k0 + cs * 8,
                        (char*)Bs + (w * 256 + r * 64) * 16);
        }
        __syncthreads();
#pragma unroll
        for (int kk = 0; kk < 2; ++kk) {
            bf16x8 af[4], bfr[4];
            const int ch = (kk * 4 + l4) ^ l7;
#pragma unroll
            for (int m = 0; m < 4; ++m) {
                const int row = wr * 64 + m * 16 + l15;
                af[m] = *(const bf16x8*)((const char*)As + row * 128 + ch * 16);
            }
#pragma unroll
            for (int n = 0; n < 4; ++n) {
                const int row = wc * 64 + n * 16 + l15;
                bfr[n] = *(const bf16x8*)((const char*)Bs + row * 128 + ch * 16);
            }
#pragma unroll
            for (int m = 0; m < 4; ++m)
#pragma unroll
                for (int n = 0; n < 4; ++n)
                    acc[m][n] = __builtin_amdgcn_mfma_f32_16x16x32_bf16(af[m], bfr[n], acc[m][n], 0, 0, 0);
        }
        __syncthreads();
    }

    // epilogue: C row = m0+wr*64+m*16+(l>>4)*4+j, col = n0+wc*64+n*16+(l&15)
    float bv[4];
#pragma unroll
    for (int n = 0; n < 4; ++n) bv[n] = bias[n0 + wc * 64 + n * 16 + l15];

#pragma unroll
    for (int m = 0; m < 4; ++m) {
#pragma unroll
        for (int j = 0; j < 4; ++j) {
            const int row = m0 + wr * 64 + m * 16 + l4 * 4 + j;
#pragma unroll
            for (int n = 0; n < 4; ++n) {
                const int col = n0 + wc * 64 + n * 16 + l15;
                const float val = acc[m][n][j] + bv[n];
                if (OUT_BF16) ((unsigned short*)Cout)[(size_t)row * N + col] = f2bf(val);
                else          ((float*)Cout)[(size_t)row * N + col] = val;
            }
        }
    }
}

// ---------------------------------------------------------------------------
// Causal flash attention, bf16 MFMA (32x32x16), fp32 accum/softmax.
// v4: TRIANGLE-PAIRED blocks for uniform work.  grid = (16, B*H), 256 thr.
// Block j: strip A = q rows [64j, 64j+64) (waves 0,1),
//          strip B = q rows [1984-64j, 2048-64j) (waves 2,3).
// One shared KV sweep of T = 32-j tiles covers both strips (A's tiles are a
// prefix).  Active wave-tiles per block = 2(j+1)+2(32-j) = 66 — uniform.
// Double-buffered K/Vt staging (32KB), prefetch issued before compute.
//  - S^T = K @ Q^T  (lane&31 = q -> softmax lane-local + 1 shfl_xor(32))
//  - O^T = Vt @ P   (lane&31 = q -> rescale lane-local)
//  - defer-max (THR=8): skip O-rescale when tile max grew < 8.
// ---------------------------------------------------------------------------
__global__ __launch_bounds__(256, 4)
void attn_bf16(const unsigned short* __restrict__ qkv, unsigned short* __restrict__ aout)
{
    __shared__ unsigned short Ks[2][64 * 64];   // [buf][kv][hd], chunk^=(row&7)
    __shared__ unsigned short Vt[2][64 * 64];   // [buf][d][kv],  chunk^=(d&7)

    const int tid = threadIdx.x;
    const int w = tid >> 6, ln = tid & 63;
    const int l31 = ln & 31, hi = ln >> 5;
    const int bh = blockIdx.y, b = bh >> 4, h = bh & 15;
    const int j = blockIdx.x;                       // 0..15, heavy first
    const int q0s = (w < 2) ? (64 * j) : (1984 - 64 * j);
    const int qbase = q0s + 32 * (w & 1);           // this wave's 32 q rows
    const int T = 32 - j;                           // KV tiles staged
    const size_t rowb = (size_t)b * SS;

    // ---- Q fragments (32 rows), scaled by 1/8 folded into bf16 ----
    bf16x8 qf[4];
    {
        const int qrow = qbase + l31;
        const unsigned short* qp = qkv + (rowb + qrow) * N3 + h * HD + hi * 8;
#pragma unroll
        for (int kg = 0; kg < 4; ++kg) {
            uint4 u = *(const uint4*)(qp + kg * 16);
            unsigned int* pin = (unsigned int*)&u;
            unsigned int ro[4];
#pragma unroll
            for (int e = 0; e < 4; ++e) {
                const unsigned int pw = pin[e];
                const float f0 = fromraw(pw << 16) * 0.125f;
                const float f1 = fromraw(pw & 0xffff0000u) * 0.125f;
                ro[e] = (unsigned)f2bf(f0) | ((unsigned)f2bf(f1) << 16);
            }
            U128 o; o.u = make_uint4(ro[0], ro[1], ro[2], ro[3]);
            qf[kg] = o.v;
        }
    }

    f32x16 ot[2];                          // [d-tile], O^T accumulators
    ot[0] = zero16(); ot[1] = zero16();
    float mrun = -1e30f, lrun = 0.f;

    // V-prefetch registers (per thread: 2 kv rows x 8 d)
    const int kv0 = (tid & 31) * 2, d0v = (tid >> 5) * 8;
    uint4 vr0, vr1;

    // ---- staging helpers (all 256 threads) ----
    auto stageK = [&](int t, int bf) {
#pragma unroll
        for (int r = 0; r < 2; ++r) {
            const int slot = r * 256 + tid;
            const int row = slot >> 3, ch = slot & 7;
            const int cs = ch ^ (row & 7);
            gload_lds16(qkv + (rowb + t * 64 + row) * N3 + DD + h * HD + cs * 8,
                        (char*)Ks[bf] + slot * 16);
        }
    };
    auto loadV = [&](int t) {
        const unsigned short* gv = qkv + (rowb + t * 64 + kv0) * N3 + 2 * DD + h * HD + d0v;
        vr0 = *(const uint4*)gv;
        vr1 = *(const uint4*)(gv + N3);
    };
    auto writeVt = [&](int bf) {
        const unsigned int* a0 = (const unsigned int*)&vr0;
        const unsigned int* a1 = (const unsigned int*)&vr1;
#pragma unroll
        for (int e2 = 0; e2 < 4; ++e2) {
            const unsigned int w0 = a0[e2], w1 = a1[e2];
            const int dl = d0v + 2 * e2, dh = dl + 1;
            const unsigned int lo = (w0 & 0xffffu) | (w1 << 16);
            const unsigned int hp = (w0 >> 16) | (w1 & 0xffff0000u);
            *(unsigned int*)((char*)Vt[bf] + dl * 128 + (((kv0 >> 3) ^ (dl & 7)) << 4) + (kv0 & 7) * 2) = lo;
            *(unsigned int*)((char*)Vt[bf] + dh * 128 + (((kv0 >> 3) ^ (dh & 7)) << 4) + (kv0 & 7) * 2) = hp;
        }
    };

    // ---- prologue: stage tile 0 into buf 0 ----
    stageK(0, 0);
    loadV(0);
    asm volatile("s_waitcnt vmcnt(0)" ::: "memory");
    writeVt(0);
    __syncthreads();

    int buf = 0;
    for (int t = 0; t < T; ++t) {
        const int kvb = t * 64;
        const bool pre = (t + 1 < T);
        if (pre) { stageK(t + 1, buf ^ 1); loadV(t + 1); }   // async prefetch

        if (kvb <= qbase + 31) {           // wave-uniform: this wave has work
            // ---- K fragments ----
            bf16x8 kf[2][4];               // [kv-half][k-group]
#pragma unroll
            for (int kvt = 0; kvt < 2; ++kvt) {
                const int row = kvt * 32 + l31;
#pragma unroll
                for (int kg = 0; kg < 4; ++kg) {
                    const int ch = (kg * 2 + hi) ^ (row & 7);
                    kf[kvt][kg] = *(const bf16x8*)((const char*)Ks[buf] + row * 128 + ch * 16);
                }
            }
            // ---- scores ----
            f32x16 s[2];
            s[0] = zero16(); s[1] = zero16();
#pragma unroll
            for (int kg = 0; kg < 4; ++kg) {
                s[0] = __builtin_amdgcn_mfma_f32_32x32x16_bf16(kf[0][kg], qf[kg], s[0], 0, 0, 0);
                s[1] = __builtin_amdgcn_mfma_f32_32x32x16_bf16(kf[1][kg], qf[kg], s[1], 0, 0, 0);
            }
            // ---- V fragments ----
            bf16x8 vf[2][4];               // [d-tile][kv-group]
#pragma unroll
            for (int dt = 0; dt < 2; ++dt) {
                const int row = dt * 32 + l31;
#pragma unroll
                for (int g = 0; g < 4; ++g) {
                    const int ch = (g * 2 + hi) ^ (row & 7);
                    vf[dt][g] = *(const bf16x8*)((const char*)Vt[buf] + row * 128 + ch * 16);
                }
            }

            // ---- mask, online softmax (defer-max), pack P, PV ----
            const int qg = qbase + l31;
            float sv[32];
#pragma unroll
            for (int r = 0; r < 16; ++r) { sv[r] = s[0][r]; sv[16 + r] = s[1][r]; }
            if (kvb + 63 > qbase) {        // tile touches/passes the diagonal
#pragma unroll
                for (int kvt = 0; kvt < 2; ++kvt)
#pragma unroll
                    for (int r = 0; r < 16; ++r) {
                        const int kvg = kvb + kvt * 32 + (r & 3) + 8 * (r >> 2) + 4 * hi;
                        if (kvg > qg) sv[kvt * 16 + r] = -1e30f;
                    }
            }
            float mt = sv[0];
#pragma unroll
            for (int r = 1; r < 32; ++r) mt = fmaxf(mt, sv[r]);
            mt = fmaxf(mt, __shfl_xor(mt, 32));

            if (__all(mt <= mrun + 8.f)) {
                // defer-max: keep old max, no rescale (P bounded by e^8)
                float lt = 0.f;
#pragma unroll
                for (int r = 0; r < 32; ++r) { sv[r] = __expf(sv[r] - mrun); lt += sv[r]; }
                lt += __shfl_xor(lt, 32);
                lrun += lt;
            } else {
                const float mnew = fmaxf(mrun, mt);
                const float corr = __expf(mrun - mnew);
                mrun = mnew;
                float lt = 0.f;
#pragma unroll
                for (int r = 0; r < 32; ++r) { sv[r] = __expf(sv[r] - mnew); lt += sv[r]; }
                lt += __shfl_xor(lt, 32);
                lrun = lrun * corr + lt;
#pragma unroll
                for (int dt = 0; dt < 2; ++dt)
#pragma unroll
                    for (int r = 0; r < 16; ++r) ot[dt][r] *= corr;
            }

            // pack P to bf16 pairs
            unsigned int c[16];
#pragma unroll
            for (int k = 0; k < 8; ++k)
                c[k] = (unsigned)f2bf(sv[2 * k]) | ((unsigned)f2bf(sv[2 * k + 1]) << 16);
#pragma unroll
            for (int k = 0; k < 8; ++k)
                c[8 + k] = (unsigned)f2bf(sv[16 + 2 * k]) | ((unsigned)f2bf(sv[16 + 2 * k + 1]) << 16);
            // exchange with partner lane (ln ^ 32)
            unsigned int rp[8];
#pragma unroll
            for (int tt = 0; tt < 2; ++tt) {
                const unsigned int s0_ = hi ? c[tt * 8 + 0] : c[tt * 8 + 2];
                const unsigned int s1_ = hi ? c[tt * 8 + 1] : c[tt * 8 + 3];
                const unsigned int s2_ = hi ? c[tt * 8 + 4] : c[tt * 8 + 6];
                const unsigned int s3_ = hi ? c[tt * 8 + 5] : c[tt * 8 + 7];
                rp[tt * 4 + 0] = (unsigned)__shfl_xor((int)s0_, 32);
                rp[tt * 4 + 1] = (unsigned)__shfl_xor((int)s1_, 32);
                rp[tt * 4 + 2] = (unsigned)__shfl_xor((int)s2_, 32);
                rp[tt * 4 + 3] = (unsigned)__shfl_xor((int)s3_, 32);
            }
            // build P fragments pa[g]: elem j = P[kv = 16g + 8*hi + j][q]
            bf16x8 pa[4];
#pragma unroll
            for (int tt = 0; tt < 2; ++tt) {
                U128 w0, w1;
                if (hi) {
                    w0.u = make_uint4(rp[tt * 4 + 0], rp[tt * 4 + 1], c[tt * 8 + 2], c[tt * 8 + 3]);
                    w1.u = make_uint4(rp[tt * 4 + 2], rp[tt * 4 + 3], c[tt * 8 + 6], c[tt * 8 + 7]);
                } else {
                    w0.u = make_uint4(c[tt * 8 + 0], c[tt * 8 + 1], rp[tt * 4 + 0], rp[tt * 4 + 1]);
                    w1.u = make_uint4(c[tt * 8 + 4], c[tt * 8 + 5], rp[tt * 4 + 2], rp[tt * 4 + 3]);
                }
                pa[2 * tt] = w0.v; pa[2 * tt + 1] = w1.v;
            }
            // PV: O^T[d][q] += Vt-frag * P-frag
#pragma unroll
            for (int dt = 0; dt < 2; ++dt)
#pragma unroll
                for (int g = 0; g < 4; ++g)
                    ot[dt] = __builtin_amdgcn_mfma_f32_32x32x16_bf16(vf[dt][g], pa[g], ot[dt], 0, 0, 0);
        }

        asm volatile("s_waitcnt vmcnt(0)" ::: "memory");  // prefetch landed
        __syncthreads();                   // all waves done reading buf
        if (pre) writeVt(buf ^ 1);         // transpose-write V(t+1)
        __syncthreads();                   // Vt[b^1] visible to all
        buf ^= 1;
    }

    // ---- epilogue: normalize, store bf16 (pairs of adjacent d) ----
    {
        const float inv = 1.f / lrun;
        const int qrow = qbase + l31;
        unsigned short* orow = aout + (rowb + qrow) * DD + h * HD;
#pragma unroll
        for (int dt = 0; dt < 2; ++dt)
#pragma unroll
            for (int k = 0; k < 8; ++k) {
                const int r0 = 2 * k;
                const int d = dt * 32 + (r0 & 3) + 8 * (r0 >> 2) + 4 * hi;
                const unsigned int pv = (unsigned)f2bf(ot[dt][r0] * inv)
                                      | ((unsigned)f2bf(ot[dt][r0 + 1] * inv) << 16);
                *(unsigned int*)(orow + d) = pv;
            }
    }
}

// ---------------------------------------------------------------------------
extern "C" void kernel_launch(void* const* d_in, const int* in_sizes, int n_in,
                              void* d_out, int out_size, void* d_ws, size_t ws_size,
                              hipStream_t stream)
{
    const float* hidden   = (const float*)d_in[0];
    const float* c_attn_w = (const float*)d_in[1];
    const float* c_attn_b = (const float*)d_in[2];
    const float* c_proj_w = (const float*)d_in[3];
    const float* c_proj_b = (const float*)d_in[4];
    float* outp = (float*)d_out;

    char* ws = (char*)d_ws;
    unsigned short* hb   = (unsigned short*)ws;                       ws += (size_t)MM * DD * 2;   // 8 MB
    unsigned short* wt1  = (unsigned short*)ws;                       ws += (size_t)N3 * DD * 2;   // 6 MB
    unsigned short* wt2  = (unsigned short*)ws;                       ws += (size_t)DD * DD * 2;   // 2 MB
    unsigned short* qkv  = (unsigned short*)ws;                       ws += (size_t)MM * N3 * 2;   // 24 MB
    unsigned short* aov  = (unsigned short*)ws;                                                    // 8 MB

    // casts / weight transposes
    cast_bf16_kernel<<<(MM * DD) / 2048, 256, 0, stream>>>(hidden, hb);
    transpose_cast_kernel<<<dim3(N3 / 32, DD / 32), 256, 0, stream>>>(c_attn_w, wt1, DD, N3);
    transpose_cast_kernel<<<dim3(DD / 32, DD / 32), 256, 0, stream>>>(c_proj_w, wt2, DD, DD);

    // QKV projection: [4096,1024] @ [1024,3072] + b -> bf16
    gemm_bf16<1><<<dim3(N3 / 128, MM / 128), 256, 0, stream>>>(hb, wt1, c_attn_b, qkv, MM, N3, DD);

    // causal flash attention -> bf16 merged-head [4096][1024]
    // triangle-paired: 16 x 32 blocks, uniform 66 active wave-tiles/block
    attn_bf16<<<dim3(16, BB * HH), 256, 0, stream>>>(qkv, aov);

    // output projection: [4096,1024] @ [1024,1024] + b -> fp32
    gemm_bf16<0><<<dim3(DD / 128, MM / 128), 256, 0, stream>>>(aov, wt2, c_proj_b, outp, MM, DD, DD);
}

// Round 11
// 224.869 us; speedup vs baseline: 2.2665x; 2.2665x over previous
//
#include <hip/hip_runtime.h>
#include <hip/hip_bf16.h>
#include <math.h>

// Problem: B=2, S=2048, D=1024, H=16, hd=64
#define BB 2
#define SS 2048
#define DD 1024
#define HH 16
#define HD 64
#define MM (BB*SS)      // 4096
#define N3 (3*DD)       // 3072

using bf16x8 = __attribute__((ext_vector_type(8))) short;
using f32x4  = __attribute__((ext_vector_type(4))) float;
using f32x16 = __attribute__((ext_vector_type(16))) float;

union U128 { uint4 u; bf16x8 v; };

#define GLOBAL_AS __attribute__((address_space(1)))
#define LDS_AS    __attribute__((address_space(3)))

__device__ __forceinline__ void gload_lds16(const void* g, void* l) {
    __builtin_amdgcn_global_load_lds((const GLOBAL_AS void*)g, (LDS_AS void*)l, 16, 0, 0);
}

__device__ __forceinline__ unsigned short f2bf(float f) {
    union { float f; unsigned int u; } x; x.f = f;
    unsigned int u = x.u;
    unsigned int r = (u + 0x7fffu + ((u >> 16) & 1u)) >> 16;   // RNE
    return (unsigned short)r;
}
__device__ __forceinline__ float fromraw(unsigned int u) {
    union { unsigned int u; float f; } x; x.u = u; return x.f;
}
__device__ __forceinline__ f32x16 zero16() {
    f32x16 v;
#pragma unroll
    for (int i = 0; i < 16; ++i) v[i] = 0.f;
    return v;
}

// ---------------------------------------------------------------------------
// Elementwise fp32 -> bf16 cast (8 elems/thread). n must be divisible by 2048.
// ---------------------------------------------------------------------------
__global__ __launch_bounds__(256)
void cast_bf16_kernel(const float* __restrict__ X, unsigned short* __restrict__ Y)
{
    int i = blockIdx.x * 256 + threadIdx.x;
    const float4 a = ((const float4*)X)[i * 2];
    const float4 b = ((const float4*)X)[i * 2 + 1];
    uint4 o;
    o.x = (unsigned)f2bf(a.x) | ((unsigned)f2bf(a.y) << 16);
    o.y = (unsigned)f2bf(a.z) | ((unsigned)f2bf(a.w) << 16);
    o.z = (unsigned)f2bf(b.x) | ((unsigned)f2bf(b.y) << 16);
    o.w = (unsigned)f2bf(b.z) | ((unsigned)f2bf(b.w) << 16);
    ((uint4*)Y)[i] = o;
}

// ---------------------------------------------------------------------------
// Transpose+cast: W[K][N] fp32 -> Wt[N][K] bf16.  32x32 tiles, 256 threads.
// ---------------------------------------------------------------------------
__global__ __launch_bounds__(256)
void transpose_cast_kernel(const float* __restrict__ W, unsigned short* __restrict__ Wt,
                           int K, int N)
{
    __shared__ float t[32][33];
    const int n0 = blockIdx.x * 32, k0 = blockIdx.y * 32;
    const int tr = threadIdx.x >> 3, c4 = (threadIdx.x & 7) * 4;
    float4 v = *(const float4*)(W + (size_t)(k0 + tr) * N + n0 + c4);
    t[tr][c4 + 0] = v.x; t[tr][c4 + 1] = v.y; t[tr][c4 + 2] = v.z; t[tr][c4 + 3] = v.w;
    __syncthreads();
    unsigned int o0 = (unsigned)f2bf(t[c4 + 0][tr]) | ((unsigned)f2bf(t[c4 + 1][tr]) << 16);
    unsigned int o1 = (unsigned)f2bf(t[c4 + 2][tr]) | ((unsigned)f2bf(t[c4 + 3][tr]) << 16);
    uint2 o; o.x = o0; o.y = o1;
    *(uint2*)(Wt + (size_t)(n0 + tr) * K + k0 + c4) = o;
}

// ---------------------------------------------------------------------------
// bf16 MFMA GEMM:  C[M][N] = A[M][K] @ Bt[N][K]^T + bias[N]
// A, Bt bf16 row-major (both k-contiguous).  128x128 tile, BK=64, 4 waves 2x2.
// LDS tiles [128 rows][64 k] with 16B-chunk XOR swizzle (chunk ^= row&7),
// staged via global_load_lds with pre-swizzled global source addresses.
// OUT_BF16: 1 -> bf16 output, 0 -> fp32 output.
// ---------------------------------------------------------------------------
template<int OUT_BF16>
__global__ __launch_bounds__(256)
void gemm_bf16(const unsigned short* __restrict__ A, const unsigned short* __restrict__ Bt,
               const float* __restrict__ bias, void* __restrict__ Cout,
               int M, int N, int K)
{
    __shared__ unsigned short As[128 * 64];
    __shared__ unsigned short Bs[128 * 64];

    const int tid = threadIdx.x;
    const int w = tid >> 6, ln = tid & 63;
    const int m0 = blockIdx.y * 128, n0 = blockIdx.x * 128;
    const int wr = w >> 1, wc = w & 1;
    const int l15 = ln & 15, l4 = ln >> 4, l7 = ln & 7;

    f32x4 acc[4][4];
#pragma unroll
    for (int m = 0; m < 4; ++m)
#pragma unroll
        for (int n = 0; n < 4; ++n) {
            f32x4 z = {0.f, 0.f, 0.f, 0.f};
            acc[m][n] = z;
        }

    for (int k0 = 0; k0 < K; k0 += 64) {
        // stage A and B tiles (each 16KB = 1024 16B-slots; 4 instrs/wave each)
#pragma unroll
        for (int r = 0; r < 4; ++r) {
            const int slot = w * 256 + r * 64 + ln;
            const int row = slot >> 3, ch = slot & 7;
            const int cs = ch ^ (row & 7);                 // pre-swizzled source chunk
            gload_lds16(A + (size_t)(m0 + row) * K + k0 + cs * 8,
                        (char*)As + (w * 256 + r * 64) * 16);
            gload_lds16(Bt + (size_t)(n0 + row) * K + k0 + cs * 8,
                        (char*)Bs + (w * 256 + r * 64) * 16);
        }
        __syncthreads();
#pragma unroll
        for (int kk = 0; kk < 2; ++kk) {
            bf16x8 af[4], bfr[4];
            const int ch = (kk * 4 + l4) ^ l7;
#pragma unroll
            for (int m = 0; m < 4; ++m) {
                const int row = wr * 64 + m * 16 + l15;
                af[m] = *(const bf16x8*)((const char*)As + row * 128 + ch * 16);
            }
#pragma unroll
            for (int n = 0; n < 4; ++n) {
                const int row = wc * 64 + n * 16 + l15;
                bfr[n] = *(const bf16x8*)((const char*)Bs + row * 128 + ch * 16);
            }
#pragma unroll
            for (int m = 0; m < 4; ++m)
#pragma unroll
                for (int n = 0; n < 4; ++n)
                    acc[m][n] = __builtin_amdgcn_mfma_f32_16x16x32_bf16(af[m], bfr[n], acc[m][n], 0, 0, 0);
        }
        __syncthreads();
    }

    // epilogue: C row = m0+wr*64+m*16+(l>>4)*4+j, col = n0+wc*64+n*16+(l&15)
    float bv[4];
#pragma unroll
    for (int n = 0; n < 4; ++n) bv[n] = bias[n0 + wc * 64 + n * 16 + l15];

#pragma unroll
    for (int m = 0; m < 4; ++m) {
#pragma unroll
        for (int j = 0; j < 4; ++j) {
            const int row = m0 + wr * 64 + m * 16 + l4 * 4 + j;
#pragma unroll
            for (int n = 0; n < 4; ++n) {
                const int col = n0 + wc * 64 + n * 16 + l15;
                const float val = acc[m][n][j] + bv[n];
                if (OUT_BF16) ((unsigned short*)Cout)[(size_t)row * N + col] = f2bf(val);
                else          ((float*)Cout)[(size_t)row * N + col] = val;
            }
        }
    }
}

// ---------------------------------------------------------------------------
// Causal flash attention, bf16 MFMA (32x32x16), fp32 accum/softmax.
// v5 = v4 minus the VGPR-squeeze: __launch_bounds__(256, 2) (the (256,4) of
// v4 forced VGPR 88->64 and spilled softmax state to scratch: WRITE_SIZE
// 8MB -> 580MB, attn 89 -> 364us.  Round-7 footprint restored.)
// TRIANGLE-PAIRED blocks for uniform work.  grid = (16, B*H), 256 thr.
// Block j: strip A = q rows [64j, 64j+64) (waves 0,1),
//          strip B = q rows [1984-64j, 2048-64j) (waves 2,3).
// One shared KV sweep of T = 32-j tiles covers both strips (A's tiles are a
// prefix).  Active wave-tiles per block = 2(j+1)+2(32-j) = 66 — uniform.
// Double-buffered K/Vt staging (32KB), prefetch issued before compute.
//  - S^T = K @ Q^T  (lane&31 = q -> softmax lane-local + 1 shfl_xor(32))
//  - O^T = Vt @ P   (lane&31 = q -> rescale lane-local)
//  - defer-max (THR=8): skip O-rescale when tile max grew < 8.
// ---------------------------------------------------------------------------
__global__ __launch_bounds__(256, 2)
void attn_bf16(const unsigned short* __restrict__ qkv, unsigned short* __restrict__ aout)
{
    __shared__ unsigned short Ks[2][64 * 64];   // [buf][kv][hd], chunk^=(row&7)
    __shared__ unsigned short Vt[2][64 * 64];   // [buf][d][kv],  chunk^=(d&7)

    const int tid = threadIdx.x;
    const int w = tid >> 6, ln = tid & 63;
    const int l31 = ln & 31, hi = ln >> 5;
    const int bh = blockIdx.y, b = bh >> 4, h = bh & 15;
    const int j = blockIdx.x;                       // 0..15, heavy first
    const int q0s = (w < 2) ? (64 * j) : (1984 - 64 * j);
    const int qbase = q0s + 32 * (w & 1);           // this wave's 32 q rows
    const int T = 32 - j;                           // KV tiles staged
    const size_t rowb = (size_t)b * SS;

    // ---- Q fragments (32 rows), scaled by 1/8 folded into bf16 ----
    bf16x8 qf[4];
    {
        const int qrow = qbase + l31;
        const unsigned short* qp = qkv + (rowb + qrow) * N3 + h * HD + hi * 8;
#pragma unroll
        for (int kg = 0; kg < 4; ++kg) {
            uint4 u = *(const uint4*)(qp + kg * 16);
            unsigned int* pin = (unsigned int*)&u;
            unsigned int ro[4];
#pragma unroll
            for (int e = 0; e < 4; ++e) {
                const unsigned int pw = pin[e];
                const float f0 = fromraw(pw << 16) * 0.125f;
                const float f1 = fromraw(pw & 0xffff0000u) * 0.125f;
                ro[e] = (unsigned)f2bf(f0) | ((unsigned)f2bf(f1) << 16);
            }
            U128 o; o.u = make_uint4(ro[0], ro[1], ro[2], ro[3]);
            qf[kg] = o.v;
        }
    }

    f32x16 ot[2];                          // [d-tile], O^T accumulators
    ot[0] = zero16(); ot[1] = zero16();
    float mrun = -1e30f, lrun = 0.f;

    // V-prefetch registers (per thread: 2 kv rows x 8 d)
    const int kv0 = (tid & 31) * 2, d0v = (tid >> 5) * 8;
    uint4 vr0, vr1;

    // ---- staging helpers (all 256 threads) ----
    auto stageK = [&](int t, int bf) {
#pragma unroll
        for (int r = 0; r < 2; ++r) {
            const int slot = r * 256 + tid;
            const int row = slot >> 3, ch = slot & 7;
            const int cs = ch ^ (row & 7);
            gload_lds16(qkv + (rowb + t * 64 + row) * N3 + DD + h * HD + cs * 8,
                        (char*)Ks[bf] + slot * 16);
        }
    };
    auto loadV = [&](int t) {
        const unsigned short* gv = qkv + (rowb + t * 64 + kv0) * N3 + 2 * DD + h * HD + d0v;
        vr0 = *(const uint4*)gv;
        vr1 = *(const uint4*)(gv + N3);
    };
    auto writeVt = [&](int bf) {
        const unsigned int* a0 = (const unsigned int*)&vr0;
        const unsigned int* a1 = (const unsigned int*)&vr1;
#pragma unroll
        for (int e2 = 0; e2 < 4; ++e2) {
            const unsigned int w0 = a0[e2], w1 = a1[e2];
            const int dl = d0v + 2 * e2, dh = dl + 1;
            const unsigned int lo = (w0 & 0xffffu) | (w1 << 16);
            const unsigned int hp = (w0 >> 16) | (w1 & 0xffff0000u);
            *(unsigned int*)((char*)Vt[bf] + dl * 128 + (((kv0 >> 3) ^ (dl & 7)) << 4) + (kv0 & 7) * 2) = lo;
            *(unsigned int*)((char*)Vt[bf] + dh * 128 + (((kv0 >> 3) ^ (dh & 7)) << 4) + (kv0 & 7) * 2) = hp;
        }
    };

    // ---- prologue: stage tile 0 into buf 0 ----
    stageK(0, 0);
    loadV(0);
    asm volatile("s_waitcnt vmcnt(0)" ::: "memory");
    writeVt(0);
    __syncthreads();

    int buf = 0;
    for (int t = 0; t < T; ++t) {
        const int kvb = t * 64;
        const bool pre = (t + 1 < T);
        if (pre) { stageK(t + 1, buf ^ 1); loadV(t + 1); }   // async prefetch

        if (kvb <= qbase + 31) {           // wave-uniform: this wave has work
            // ---- K fragments ----
            bf16x8 kf[2][4];               // [kv-half][k-group]
#pragma unroll
            for (int kvt = 0; kvt < 2; ++kvt) {
                const int row = kvt * 32 + l31;
#pragma unroll
                for (int kg = 0; kg < 4; ++kg) {
                    const int ch = (kg * 2 + hi) ^ (row & 7);
                    kf[kvt][kg] = *(const bf16x8*)((const char*)Ks[buf] + row * 128 + ch * 16);
                }
            }
            // ---- scores ----
            f32x16 s[2];
            s[0] = zero16(); s[1] = zero16();
#pragma unroll
            for (int kg = 0; kg < 4; ++kg) {
                s[0] = __builtin_amdgcn_mfma_f32_32x32x16_bf16(kf[0][kg], qf[kg], s[0], 0, 0, 0);
                s[1] = __builtin_amdgcn_mfma_f32_32x32x16_bf16(kf[1][kg], qf[kg], s[1], 0, 0, 0);
            }
            // ---- V fragments ----
            bf16x8 vf[2][4];               // [d-tile][kv-group]
#pragma unroll
            for (int dt = 0; dt < 2; ++dt) {
                const int row = dt * 32 + l31;
#pragma unroll
                for (int g = 0; g < 4; ++g) {
                    const int ch = (g * 2 + hi) ^ (row & 7);
                    vf[dt][g] = *(const bf16x8*)((const char*)Vt[buf] + row * 128 + ch * 16);
                }
            }

            // ---- mask, online softmax (defer-max), pack P, PV ----
            const int qg = qbase + l31;
            float sv[32];
#pragma unroll
            for (int r = 0; r < 16; ++r) { sv[r] = s[0][r]; sv[16 + r] = s[1][r]; }
            if (kvb + 63 > qbase) {        // tile touches/passes the diagonal
#pragma unroll
                for (int kvt = 0; kvt < 2; ++kvt)
#pragma unroll
                    for (int r = 0; r < 16; ++r) {
                        const int kvg = kvb + kvt * 32 + (r & 3) + 8 * (r >> 2) + 4 * hi;
                        if (kvg > qg) sv[kvt * 16 + r] = -1e30f;
                    }
            }
            float mt = sv[0];
#pragma unroll
            for (int r = 1; r < 32; ++r) mt = fmaxf(mt, sv[r]);
            mt = fmaxf(mt, __shfl_xor(mt, 32));

            if (__all(mt <= mrun + 8.f)) {
                // defer-max: keep old max, no rescale (P bounded by e^8)
                float lt = 0.f;
#pragma unroll
                for (int r = 0; r < 32; ++r) { sv[r] = __expf(sv[r] - mrun); lt += sv[r]; }
                lt += __shfl_xor(lt, 32);
                lrun += lt;
            } else {
                const float mnew = fmaxf(mrun, mt);
                const float corr = __expf(mrun - mnew);
                mrun = mnew;
                float lt = 0.f;
#pragma unroll
                for (int r = 0; r < 32; ++r) { sv[r] = __expf(sv[r] - mnew); lt += sv[r]; }
                lt += __shfl_xor(lt, 32);
                lrun = lrun * corr + lt;
#pragma unroll
                for (int dt = 0; dt < 2; ++dt)
#pragma unroll
                    for (int r = 0; r < 16; ++r) ot[dt][r] *= corr;
            }

            // pack P to bf16 pairs
            unsigned int c[16];
#pragma unroll
            for (int k = 0; k < 8; ++k)
                c[k] = (unsigned)f2bf(sv[2 * k]) | ((unsigned)f2bf(sv[2 * k + 1]) << 16);
#pragma unroll
            for (int k = 0; k < 8; ++k)
                c[8 + k] = (unsigned)f2bf(sv[16 + 2 * k]) | ((unsigned)f2bf(sv[16 + 2 * k + 1]) << 16);
            // exchange with partner lane (ln ^ 32)
            unsigned int rp[8];
#pragma unroll
            for (int tt = 0; tt < 2; ++tt) {
                const unsigned int s0_ = hi ? c[tt * 8 + 0] : c[tt * 8 + 2];
                const unsigned int s1_ = hi ? c[tt * 8 + 1] : c[tt * 8 + 3];
                const unsigned int s2_ = hi ? c[tt * 8 + 4] : c[tt * 8 + 6];
                const unsigned int s3_ = hi ? c[tt * 8 + 5] : c[tt * 8 + 7];
                rp[tt * 4 + 0] = (unsigned)__shfl_xor((int)s0_, 32);
                rp[tt * 4 + 1] = (unsigned)__shfl_xor((int)s1_, 32);
                rp[tt * 4 + 2] = (unsigned)__shfl_xor((int)s2_, 32);
                rp[tt * 4 + 3] = (unsigned)__shfl_xor((int)s3_, 32);
            }
            // build P fragments pa[g]: elem j = P[kv = 16g + 8*hi + j][q]
            bf16x8 pa[4];
#pragma unroll
            for (int tt = 0; tt < 2; ++tt) {
                U128 w0, w1;
                if (hi) {
                    w0.u = make_uint4(rp[tt * 4 + 0], rp[tt * 4 + 1], c[tt * 8 + 2], c[tt * 8 + 3]);
                    w1.u = make_uint4(rp[tt * 4 + 2], rp[tt * 4 + 3], c[tt * 8 + 6], c[tt * 8 + 7]);
                } else {
                    w0.u = make_uint4(c[tt * 8 + 0], c[tt * 8 + 1], rp[tt * 4 + 0], rp[tt * 4 + 1]);
                    w1.u = make_uint4(c[tt * 8 + 4], c[tt * 8 + 5], rp[tt * 4 + 2], rp[tt * 4 + 3]);
                }
                pa[2 * tt] = w0.v; pa[2 * tt + 1] = w1.v;
            }
            // PV: O^T[d][q] += Vt-frag * P-frag
#pragma unroll
            for (int dt = 0; dt < 2; ++dt)
#pragma unroll
                for (int g = 0; g < 4; ++g)
                    ot[dt] = __builtin_amdgcn_mfma_f32_32x32x16_bf16(vf[dt][g], pa[g], ot[dt], 0, 0, 0);
        }

        asm volatile("s_waitcnt vmcnt(0)" ::: "memory");  // prefetch landed
        __syncthreads();                   // all waves done reading buf
        if (pre) writeVt(buf ^ 1);         // transpose-write V(t+1)
        __syncthreads();                   // Vt[b^1] visible to all
        buf ^= 1;
    }

    // ---- epilogue: normalize, store bf16 (pairs of adjacent d) ----
    {
        const float inv = 1.f / lrun;
        const int qrow = qbase + l31;
        unsigned short* orow = aout + (rowb + qrow) * DD + h * HD;
#pragma unroll
        for (int dt = 0; dt < 2; ++dt)
#pragma unroll
            for (int k = 0; k < 8; ++k) {
                const int r0 = 2 * k;
                const int d = dt * 32 + (r0 & 3) + 8 * (r0 >> 2) + 4 * hi;
                const unsigned int pv = (unsigned)f2bf(ot[dt][r0] * inv)
                                      | ((unsigned)f2bf(ot[dt][r0 + 1] * inv) << 16);
                *(unsigned int*)(orow + d) = pv;
            }
    }
}

// ---------------------------------------------------------------------------
extern "C" void kernel_launch(void* const* d_in, const int* in_sizes, int n_in,
                              void* d_out, int out_size, void* d_ws, size_t ws_size,
                              hipStream_t stream)
{
    const float* hidden   = (const float*)d_in[0];
    const float* c_attn_w = (const float*)d_in[1];
    const float* c_attn_b = (const float*)d_in[2];
    const float* c_proj_w = (const float*)d_in[3];
    const float* c_proj_b = (const float*)d_in[4];
    float* outp = (float*)d_out;

    char* ws = (char*)d_ws;
    unsigned short* hb   = (unsigned short*)ws;                       ws += (size_t)MM * DD * 2;   // 8 MB
    unsigned short* wt1  = (unsigned short*)ws;                       ws += (size_t)N3 * DD * 2;   // 6 MB
    unsigned short* wt2  = (unsigned short*)ws;                       ws += (size_t)DD * DD * 2;   // 2 MB
    unsigned short* qkv  = (unsigned short*)ws;                       ws += (size_t)MM * N3 * 2;   // 24 MB
    unsigned short* aov  = (unsigned short*)ws;                                                    // 8 MB

    // casts / weight transposes
    cast_bf16_kernel<<<(MM * DD) / 2048, 256, 0, stream>>>(hidden, hb);
    transpose_cast_kernel<<<dim3(N3 / 32, DD / 32), 256, 0, stream>>>(c_attn_w, wt1, DD, N3);
    transpose_cast_kernel<<<dim3(DD / 32, DD / 32), 256, 0, stream>>>(c_proj_w, wt2, DD, DD);

    // QKV projection: [4096,1024] @ [1024,3072] + b -> bf16
    gemm_bf16<1><<<dim3(N3 / 128, MM / 128), 256, 0, stream>>>(hb, wt1, c_attn_b, qkv, MM, N3, DD);

    // causal flash attention -> bf16 merged-head [4096][1024]
    // triangle-paired: 16 x 32 blocks, uniform 66 active wave-tiles/block
    attn_bf16<<<dim3(16, BB * HH), 256, 0, stream>>>(qkv, aov);

    // output projection: [4096,1024] @ [1024,1024] + b -> fp32
    gemm_bf16<0><<<dim3(DD / 128, MM / 128), 256, 0, stream>>>(aov, wt2, c_proj_b, outp, MM, DD, DD);
}